// Round 25
// baseline (47.829 us; speedup 1.0000x reference)
//
#include <hip/hip_runtime.h>
#include <math.h>

#define NB 4      // batch
#define TD 128    // T_DEC
#define SE 1024   // S_ENC
#define DD 512    // D
#define UN 128    // UNITS
#define KSPLIT 4

// raw v_exp_f32: D = 2^S0 (operands pre-scaled by 2*log2e at proj time)
__device__ __forceinline__ float exp2_raw(float x) {
  float r;
  asm("v_exp_f32 %0, %1" : "=v"(r) : "v"(x));
  return r;
}

// ---------------------------------------------------------------------------
// K1: projections, fused KSPLIT-in-WG (R20-validated config).
// grid 288 x 512 thr (8 waves): blk 0..255 -> 16 enc rows, 256..287 -> 16 dec.
// Wave = (ks = wave&3 -> 128-k slice, rh = wave>>2 -> 8-row half).
// Thread: 8 rows x 2 u x 128 k = 16 FMA per coalesced float2 W load.
// k-partials reduced via LDS; bias + 2*log2e pre-scale fused.
// enc side: wencT[b][u][s] stores EXP2 of the scaled projection; dec side:
// wdec row-major, raw scaled (k_score exponentiates at LDS fill).
__global__ __launch_bounds__(512, 2) void k_proj(const float* __restrict__ enc,
                                                 const float* __restrict__ dec,
                                                 const float* __restrict__ W1,
                                                 const float* __restrict__ b1,
                                                 const float* __restrict__ W2,
                                                 const float* __restrict__ b2,
                                                 float* __restrict__ wencT,
                                                 float* __restrict__ wdec) {
  __shared__ __align__(16) float At[16 * DD];          // 32 KB
  __shared__ float red[KSPLIT][16][129];               // 33 KB (pad vs banks)

  const int tx = threadIdx.x;           // 0..511
  const int rb = blockIdx.x;            // 0..287
  const bool is_enc = rb < 256;
  const int row_base = rb * 16;         // global row numbering
  const float* __restrict__ src = is_enc
      ? (enc + (size_t)row_base * DD)
      : (dec + (size_t)(row_base - NB * SE) * DD);
  const float* __restrict__ W = is_enc ? W1 : W2;
  const float* __restrict__ bias = is_enc ? b1 : b2;
  const float K2 = 2.88539008f;         // 2*log2(e)

  // stage 16 rows = 8192 contiguous floats (2048 float4, 4/thread)
#pragma unroll
  for (int i = 0; i < 4; ++i) {
    const int idx = (i * 512 + tx) * 4;
    *(float4*)&At[idx] = *(const float4*)(src + idx);
  }
  __syncthreads();

  const int u2 = (tx & 63) * 2;
  const int wave = tx >> 6;             // 0..7
  const int ks = wave & 3;              // k-slice
  const int rh = wave >> 2;             // row half
  const int kb = ks * 128;
  const float* __restrict__ Wp = W + (size_t)kb * UN + u2;

  float acc[8][2] = {};
  for (int k = 0; k < 128; k += 4) {
    float4 a[8];
#pragma unroll
    for (int r = 0; r < 8; ++r)         // wave-uniform LDS broadcasts
      a[r] = *(const float4*)&At[(rh * 8 + r) * DD + kb + k];
#pragma unroll
    for (int j = 0; j < 4; ++j) {
      const float2 w = *(const float2*)(Wp + (size_t)(k + j) * UN);
#pragma unroll
      for (int r = 0; r < 8; ++r) {
        const float arj = ((const float*)&a[r])[j];
        acc[r][0] = fmaf(arj, w.x, acc[r][0]);
        acc[r][1] = fmaf(arj, w.y, acc[r][1]);
      }
    }
  }

#pragma unroll
  for (int r = 0; r < 8; ++r) {
    red[ks][rh * 8 + r][u2]     = acc[r][0];
    red[ks][rh * 8 + r][u2 + 1] = acc[r][1];
  }
  __syncthreads();

  // epilogue: 2048 outputs, 4/thread. thread = (u = tx>>2, rows (tx&3)*4..+3)
  const int u = tx >> 2;                // 0..127
  const int rq = (tx & 3) * 4;
  const float bu = bias[u];
  if (is_enc) {
    float o[4];
#pragma unroll
    for (int j = 0; j < 4; ++j) {
      const int row = rq + j;
      const float s = (red[0][row][u] + red[1][row][u]) +
                      (red[2][row][u] + red[3][row][u]);
      o[j] = exp2_raw(K2 * (s + bu));   // store EXP2 (hoisted from k_score)
    }
    const int b = row_base >> 10;
    const int s0 = row_base & 1023;
    *(float4*)(wencT + (size_t)(b * UN + u) * SE + s0 + rq) =
        make_float4(o[0], o[1], o[2], o[3]);
  } else {
    const int rb0 = row_base - NB * SE;
#pragma unroll
    for (int j = 0; j < 4; ++j) {
      const int row = rq + j;
      const float s = (red[0][row][u] + red[1][row][u]) +
                      (red[2][row][u] + red[3][row][u]);
      wdec[(size_t)(rb0 + row) * UN + u] = K2 * (s + bu);
    }
  }
}

// ---------------------------------------------------------------------------
// K2: scores + softmax — one WG (512 thr, 8 waves) per SINGLE (b, t): grid
// 512 = 2 independent WGs/CU (was 1024-thr/1 WG/CU: every barrier stalled
// all 16 waves; now the co-resident WG fills barrier/epilogue bubbles).
// Thread = (sq = tx&255 -> 4 s, uh = tx>>8 -> 64-u half). Loads stay
// wave-coalesced (64 consecutive sq per wave). Cost: wencT reuse halves
// (L2 traffic 2x) -- wins iff score was stall-bound, which the 3x
// issue-floor gap indicates.
// Per (s,u): 1 rcp + 2 fma on pre-exponentiated operands.
__global__ __launch_bounds__(512, 2) void k_score(const float* __restrict__ wdec,
                                                  const float* __restrict__ v,
                                                  const float* __restrict__ wencT,
                                                  float* __restrict__ attn) {
  __shared__ __align__(16) float wdE[UN];           // exp2 of pre-scaled wdec row
  __shared__ __align__(16) float nv2[UN];
  __shared__ __align__(16) float parts[2][SE];      // 8 KB
  __shared__ float redM[4], redS[4];

  const int wg = blockIdx.x;          // 0..511
  const int b = wg >> 7;
  const int t = wg & 127;
  const int bt = b * TD + t;
  const int tx = threadIdx.x;         // 0..511

  if (tx < UN) {
    wdE[tx] = exp2_raw(wdec[(size_t)bt * UN + tx]);
    nv2[tx] = -2.0f * v[tx];
  }
  __syncthreads();

  const int sq = tx & 255;            // s-quad 0..255
  const int uh = tx >> 8;             // u half 0/1
  const float* wp = wencT + (size_t)(b * UN + uh * 64) * SE + sq * 4;

  float a0[4] = {};
#pragma unroll 2
  for (int ui4 = 0; ui4 < 64; ui4 += 4) {
    const int u0 = uh * 64 + ui4;
    const float4 nv = *(const float4*)&nv2[u0];       // b128 broadcasts
    const float4 Ev = *(const float4*)&wdE[u0];
#pragma unroll
    for (int m = 0; m < 4; ++m) {
      const float4 ew = *(const float4*)(wp + (size_t)(ui4 + m) * SE);
      const float nvu = ((const float*)&nv)[m];
      const float E0 = ((const float*)&Ev)[m];
#pragma unroll
      for (int j = 0; j < 4; ++j) {
        const float e = ((const float*)&ew)[j];        // pre-exponentiated
        const float r0 = __builtin_amdgcn_rcpf(fmaf(e, E0, 1.0f));
        a0[j] = fmaf(nvu, r0, a0[j]);
      }
    }
  }
  *(float4*)&parts[uh][sq * 4] = make_float4(a0[0], a0[1], a0[2], a0[3]);
  __syncthreads();

  // threads 0..255: q -> 4 s-values each; cross-uh sum then block softmax
  float sc[4], pv[4];
  const int q = tx & 255;
  if (tx < 256) {
    const float4 g0 = *(const float4*)&parts[0][q * 4];
    const float4 g1 = *(const float4*)&parts[1][q * 4];
    sc[0] = g0.x + g1.x; sc[1] = g0.y + g1.y;
    sc[2] = g0.z + g1.z; sc[3] = g0.w + g1.w;
    float m = fmaxf(fmaxf(sc[0], sc[1]), fmaxf(sc[2], sc[3]));
#pragma unroll
    for (int off = 32; off; off >>= 1) m = fmaxf(m, __shfl_xor(m, off));
    if ((tx & 63) == 0) redM[tx >> 6] = m;
  }
  __syncthreads();
  if (tx < 256) {
    const float m = fmaxf(fmaxf(redM[0], redM[1]), fmaxf(redM[2], redM[3]));
    float s = 0.f;
#pragma unroll
    for (int j = 0; j < 4; ++j) { pv[j] = __expf(sc[j] - m); s += pv[j]; }
#pragma unroll
    for (int off = 32; off; off >>= 1) s += __shfl_xor(s, off);
    if ((tx & 63) == 0) redS[tx >> 6] = s;
  }
  __syncthreads();
  if (tx < 256) {
    const float s = (redS[0] + redS[1]) + (redS[2] + redS[3]);
    const float rinv = 1.0f / s;
    float* arow = attn + (size_t)bt * SE + q * 4;
    *(float4*)arow = make_float4(pv[0] * rinv, pv[1] * rinv,
                                 pv[2] * rinv, pv[3] * rinv);
  }
}

// ---------------------------------------------------------------------------
// K3: context, fused s-split-in-WG — 1024 thr, 16 s-chunks (4 waves/SIMD).
// grid 256: WG = (b, tg of 8 t-rows, dt of 128 d). Wave w covers s-chunk
// [64w, 64w+64); thread = 8t x 2d; 4 s per iter (b128 LDS broadcasts).
// 16 wave-partials reduced via LDS in fixed q-order (deterministic).
__global__ __launch_bounds__(1024, 1) void k_ctx(const float* __restrict__ attn,
                                                 const float* __restrict__ enc,
                                                 float* __restrict__ ctx) {
  __shared__ __align__(16) float at[8][SE];         // 32 KB
  __shared__ __align__(16) float red[16][8][128];   // 64 KB

  const int wg = blockIdx.x;            // 0..255
  const int dt = wg & 3;                // d-tile of 128
  const int tg = (wg >> 2) & 15;        // 8 t-rows
  const int b = wg >> 6;
  const int tx = threadIdx.x;           // 0..1023

  // stage attn rows: 8 x 1024 = 2048 float4, 2 per thread (coalesced)
#pragma unroll
  for (int i = 0; i < 2; ++i) {
    const int idx = i * 1024 + tx;      // float4 index 0..2047
    const int row = idx >> 8;           // 256 float4 per row
    const int c = (idx & 255) * 4;
    *(float4*)&at[row][c] =
        *(const float4*)(attn + (size_t)(b * TD + tg * 8 + row) * SE + c);
  }
  __syncthreads();

  const int w = tx >> 6;                // wave 0..15 -> s-chunk of 64
  const int dp = (tx & 63) * 2;         // d-pair within 128-d tile
  const int sbeg = w * 64;
  const float* ep = enc + ((size_t)b * SE + sbeg) * DD + dt * 128 + dp;

  float2 acc[8] = {};
  for (int s = 0; s < 64; s += 4) {
    float4 av[8];
#pragma unroll
    for (int t = 0; t < 8; ++t)         // wave-uniform b128 broadcasts
      av[t] = *(const float4*)&at[t][sbeg + s];
#pragma unroll
    for (int j = 0; j < 4; ++j) {
      const float2 ev = *(const float2*)(ep + (size_t)(s + j) * DD);
#pragma unroll
      for (int t = 0; t < 8; ++t) {
        const float a = ((const float*)&av[t])[j];
        acc[t].x = fmaf(a, ev.x, acc[t].x);
        acc[t].y = fmaf(a, ev.y, acc[t].y);
      }
    }
  }
#pragma unroll
  for (int t = 0; t < 8; ++t)
    *(float2*)&red[w][t][dp] = acc[t];
  __syncthreads();

  // epilogue: 8t x 128d = 1024 outputs, one per thread; fixed q-order sum
  const int t = tx >> 7;                // 0..7
  const int d = tx & 127;
  float o = 0.f;
#pragma unroll
  for (int q = 0; q < 16; ++q) o += red[q][t][d];
  ctx[(size_t)(b * TD + tg * 8 + t) * DD + dt * 128 + d] = o;
}

extern "C" void kernel_launch(void* const* d_in, const int* in_sizes, int n_in,
                              void* d_out, int out_size, void* d_ws, size_t ws_size,
                              hipStream_t stream) {
  const float* dec = (const float*)d_in[0];
  const float* enc = (const float*)d_in[1];
  const float* W1  = (const float*)d_in[2];
  const float* b1  = (const float*)d_in[3];
  const float* W2  = (const float*)d_in[4];
  const float* b2  = (const float*)d_in[5];
  const float* v   = (const float*)d_in[6];
  // d_in[7] = v_b: skipped — softmax is invariant to a uniform score shift.

  float* ctx  = (float*)d_out;                        // [4,128,512]
  float* attn = (float*)d_out + (size_t)NB * TD * DD; // [4,128,1024]

  float* ws    = (float*)d_ws;
  float* wencT = ws;                                  // [4][128][1024] 2 MB (exp2-domain)
  float* wdec  = wencT + (size_t)NB * UN * SE;        // [512][128] 256 KB

  hipLaunchKernelGGL(k_proj, dim3(288), dim3(512), 0, stream,
                     enc, dec, W1, b1, W2, b2, wencT, wdec);
  hipLaunchKernelGGL(k_score, dim3(512), dim3(512), 0, stream,
                     wdec, v, wencT, attn);
  hipLaunchKernelGGL(k_ctx, dim3(256), dim3(1024), 0, stream, attn, enc, ctx);
}

// Round 26
// 45.172 us; speedup vs baseline: 1.0588x; 1.0588x over previous
//
#include <hip/hip_runtime.h>
#include <math.h>

#define NB 4      // batch
#define TD 128    // T_DEC
#define SE 1024   // S_ENC
#define DD 512    // D
#define UN 128    // UNITS
#define KSPLIT 4

// raw v_exp_f32: D = 2^S0 (operands pre-scaled by 2*log2e at proj time)
__device__ __forceinline__ float exp2_raw(float x) {
  float r;
  asm("v_exp_f32 %0, %1" : "=v"(r) : "v"(x));
  return r;
}

// ---------------------------------------------------------------------------
// K1: projections, fused KSPLIT-in-WG (best-known config, R20/R24).
// grid 288 x 512 thr (8 waves): blk 0..255 -> 16 enc rows, 256..287 -> 16 dec.
// Wave = (ks = wave&3 -> 128-k slice, rh = wave>>2 -> 8-row half).
// Thread: 8 rows x 2 u x 128 k = 16 FMA per coalesced float2 W load.
// k-partials reduced via LDS; bias + 2*log2e pre-scale fused.
// enc side: wencT[b][u][s] stores EXP2 of the scaled projection; dec side:
// wdec row-major, raw scaled (k_score exponentiates at LDS fill).
__global__ __launch_bounds__(512, 2) void k_proj(const float* __restrict__ enc,
                                                 const float* __restrict__ dec,
                                                 const float* __restrict__ W1,
                                                 const float* __restrict__ b1,
                                                 const float* __restrict__ W2,
                                                 const float* __restrict__ b2,
                                                 float* __restrict__ wencT,
                                                 float* __restrict__ wdec) {
  __shared__ __align__(16) float At[16 * DD];          // 32 KB
  __shared__ float red[KSPLIT][16][129];               // 33 KB (pad vs banks)

  const int tx = threadIdx.x;           // 0..511
  const int rb = blockIdx.x;            // 0..287
  const bool is_enc = rb < 256;
  const int row_base = rb * 16;         // global row numbering
  const float* __restrict__ src = is_enc
      ? (enc + (size_t)row_base * DD)
      : (dec + (size_t)(row_base - NB * SE) * DD);
  const float* __restrict__ W = is_enc ? W1 : W2;
  const float* __restrict__ bias = is_enc ? b1 : b2;
  const float K2 = 2.88539008f;         // 2*log2(e)

  // stage 16 rows = 8192 contiguous floats (2048 float4, 4/thread)
#pragma unroll
  for (int i = 0; i < 4; ++i) {
    const int idx = (i * 512 + tx) * 4;
    *(float4*)&At[idx] = *(const float4*)(src + idx);
  }
  __syncthreads();

  const int u2 = (tx & 63) * 2;
  const int wave = tx >> 6;             // 0..7
  const int ks = wave & 3;              // k-slice
  const int rh = wave >> 2;             // row half
  const int kb = ks * 128;
  const float* __restrict__ Wp = W + (size_t)kb * UN + u2;

  float acc[8][2] = {};
  for (int k = 0; k < 128; k += 4) {
    float4 a[8];
#pragma unroll
    for (int r = 0; r < 8; ++r)         // wave-uniform LDS broadcasts
      a[r] = *(const float4*)&At[(rh * 8 + r) * DD + kb + k];
#pragma unroll
    for (int j = 0; j < 4; ++j) {
      const float2 w = *(const float2*)(Wp + (size_t)(k + j) * UN);
#pragma unroll
      for (int r = 0; r < 8; ++r) {
        const float arj = ((const float*)&a[r])[j];
        acc[r][0] = fmaf(arj, w.x, acc[r][0]);
        acc[r][1] = fmaf(arj, w.y, acc[r][1]);
      }
    }
  }

#pragma unroll
  for (int r = 0; r < 8; ++r) {
    red[ks][rh * 8 + r][u2]     = acc[r][0];
    red[ks][rh * 8 + r][u2 + 1] = acc[r][1];
  }
  __syncthreads();

  // epilogue: 2048 outputs, 4/thread. thread = (u = tx>>2, rows (tx&3)*4..+3)
  const int u = tx >> 2;                // 0..127
  const int rq = (tx & 3) * 4;
  const float bu = bias[u];
  if (is_enc) {
    float o[4];
#pragma unroll
    for (int j = 0; j < 4; ++j) {
      const int row = rq + j;
      const float s = (red[0][row][u] + red[1][row][u]) +
                      (red[2][row][u] + red[3][row][u]);
      o[j] = exp2_raw(K2 * (s + bu));   // store EXP2 (hoisted from k_score)
    }
    const int b = row_base >> 10;
    const int s0 = row_base & 1023;
    *(float4*)(wencT + (size_t)(b * UN + u) * SE + s0 + rq) =
        make_float4(o[0], o[1], o[2], o[3]);
  } else {
    const int rb0 = row_base - NB * SE;
#pragma unroll
    for (int j = 0; j < 4; ++j) {
      const int row = rq + j;
      const float s = (red[0][row][u] + red[1][row][u]) +
                      (red[2][row][u] + red[3][row][u]);
      wdec[(size_t)(rb0 + row) * UN + u] = K2 * (s + bu);
    }
  }
}

// ---------------------------------------------------------------------------
// K2: scores + softmax. One WG (1024 thr, 16 waves) per (b, t-pair): grid 256.
// wencT holds Ew = exp2(scaled w_enc); E_t = exp2(scaled wdec) at LDS fill.
// Per (s,u): 2 rcp + 4 fma (no exp in the inner loop).
// score' = sum_u (-2 v_u) * rcp(fma(Ew, E_t, 1)); consts dropped (softmax
// shift-invariant, incl. v_b). Best-known config (R20/R24): R23's shuffle
// variant broke coalescing; R25's 512-thr split doubled wencT traffic.
__global__ __launch_bounds__(1024, 1) void k_score(const float* __restrict__ wdec,
                                                   const float* __restrict__ v,
                                                   const float* __restrict__ wencT,
                                                   float* __restrict__ attn) {
  __shared__ __align__(16) float wdE[2][UN];        // exp2 of pre-scaled wdec
  __shared__ __align__(16) float nv2[UN];
  __shared__ __align__(16) float parts[4][2][SE];   // 32 KB
  __shared__ float redM[2][4], redS[2][4];

  const int wg = blockIdx.x;          // 0..255
  const int b = wg >> 6;
  const int t0 = (wg & 63) * 2;
  const int bt0 = b * TD + t0;
  const int tx = threadIdx.x;         // 0..1023

  if (tx < 2 * UN) {
    const int tt = tx >> 7, u = tx & 127;
    wdE[tt][u] = exp2_raw(wdec[(size_t)(bt0 + tt) * UN + u]);   // E_t[u]
    if (tx < UN) nv2[tx] = -2.0f * v[tx];
  }
  __syncthreads();

  const int sq = tx & 255;            // s-quad 0..255
  const int uq = tx >> 8;             // u quarter 0..3
  const float* wp = wencT + (size_t)(b * UN + uq * 32) * SE + sq * 4;

  float a0[4] = {}, a1[4] = {};
#pragma unroll 2
  for (int ui4 = 0; ui4 < 32; ui4 += 4) {
    const int u0 = uq * 32 + ui4;
    const float4 nv = *(const float4*)&nv2[u0];       // b128 broadcasts
    const float4 E0v = *(const float4*)&wdE[0][u0];
    const float4 E1v = *(const float4*)&wdE[1][u0];
#pragma unroll
    for (int m = 0; m < 4; ++m) {
      const float4 ew = *(const float4*)(wp + (size_t)(ui4 + m) * SE);
      const float nvu = ((const float*)&nv)[m];
      const float E0 = ((const float*)&E0v)[m];
      const float E1 = ((const float*)&E1v)[m];
#pragma unroll
      for (int j = 0; j < 4; ++j) {
        const float e = ((const float*)&ew)[j];        // pre-exponentiated
        const float r0 = __builtin_amdgcn_rcpf(fmaf(e, E0, 1.0f));
        a0[j] = fmaf(nvu, r0, a0[j]);
        const float r1 = __builtin_amdgcn_rcpf(fmaf(e, E1, 1.0f));
        a1[j] = fmaf(nvu, r1, a1[j]);
      }
    }
  }
  *(float4*)&parts[uq][0][sq * 4] = make_float4(a0[0], a0[1], a0[2], a0[3]);
  *(float4*)&parts[uq][1][sq * 4] = make_float4(a1[0], a1[1], a1[2], a1[3]);
  __syncthreads();

  // threads 0..511: tt = tx>>8, q = tx&255 -> 4 s-values each
  float sc[4], pv[4];
  const int tt = tx >> 8;             // valid for tx<512
  const int q = tx & 255;
  if (tx < 512) {
    const float4 g0 = *(const float4*)&parts[0][tt][q * 4];
    const float4 g1 = *(const float4*)&parts[1][tt][q * 4];
    const float4 g2 = *(const float4*)&parts[2][tt][q * 4];
    const float4 g3 = *(const float4*)&parts[3][tt][q * 4];
    sc[0] = (g0.x + g1.x) + (g2.x + g3.x);
    sc[1] = (g0.y + g1.y) + (g2.y + g3.y);
    sc[2] = (g0.z + g1.z) + (g2.z + g3.z);
    sc[3] = (g0.w + g1.w) + (g2.w + g3.w);
    float m = fmaxf(fmaxf(sc[0], sc[1]), fmaxf(sc[2], sc[3]));
#pragma unroll
    for (int off = 32; off; off >>= 1) m = fmaxf(m, __shfl_xor(m, off));
    if ((tx & 63) == 0) redM[tt][(tx >> 6) & 3] = m;
  }
  __syncthreads();
  if (tx < 512) {
    const float m = fmaxf(fmaxf(redM[tt][0], redM[tt][1]),
                          fmaxf(redM[tt][2], redM[tt][3]));
    float s = 0.f;
#pragma unroll
    for (int j = 0; j < 4; ++j) { pv[j] = __expf(sc[j] - m); s += pv[j]; }
#pragma unroll
    for (int off = 32; off; off >>= 1) s += __shfl_xor(s, off);
    if ((tx & 63) == 0) redS[tt][(tx >> 6) & 3] = s;
  }
  __syncthreads();
  if (tx < 512) {
    const float s = (redS[tt][0] + redS[tt][1]) + (redS[tt][2] + redS[tt][3]);
    const float rinv = 1.0f / s;
    float* arow = attn + (size_t)(bt0 + tt) * SE + q * 4;
    *(float4*)arow = make_float4(pv[0] * rinv, pv[1] * rinv, pv[2] * rinv, pv[3] * rinv);
  }
}

// ---------------------------------------------------------------------------
// K3: context, fused s-split-in-WG — 1024 thr, 16 s-chunks (4 waves/SIMD).
// grid 256: WG = (b, tg of 8 t-rows, dt of 128 d). Wave w covers s-chunk
// [64w, 64w+64); thread = 8t x 2d; 4 s per iter (b128 LDS broadcasts).
// 16 wave-partials reduced via LDS in fixed q-order (deterministic).
__global__ __launch_bounds__(1024, 1) void k_ctx(const float* __restrict__ attn,
                                                 const float* __restrict__ enc,
                                                 float* __restrict__ ctx) {
  __shared__ __align__(16) float at[8][SE];         // 32 KB
  __shared__ __align__(16) float red[16][8][128];   // 64 KB

  const int wg = blockIdx.x;            // 0..255
  const int dt = wg & 3;                // d-tile of 128
  const int tg = (wg >> 2) & 15;        // 8 t-rows
  const int b = wg >> 6;
  const int tx = threadIdx.x;           // 0..1023

  // stage attn rows: 8 x 1024 = 2048 float4, 2 per thread (coalesced)
#pragma unroll
  for (int i = 0; i < 2; ++i) {
    const int idx = i * 1024 + tx;      // float4 index 0..2047
    const int row = idx >> 8;           // 256 float4 per row
    const int c = (idx & 255) * 4;
    *(float4*)&at[row][c] =
        *(const float4*)(attn + (size_t)(b * TD + tg * 8 + row) * SE + c);
  }
  __syncthreads();

  const int w = tx >> 6;                // wave 0..15 -> s-chunk of 64
  const int dp = (tx & 63) * 2;         // d-pair within 128-d tile
  const int sbeg = w * 64;
  const float* ep = enc + ((size_t)b * SE + sbeg) * DD + dt * 128 + dp;

  float2 acc[8] = {};
  for (int s = 0; s < 64; s += 4) {
    float4 av[8];
#pragma unroll
    for (int t = 0; t < 8; ++t)         // wave-uniform b128 broadcasts
      av[t] = *(const float4*)&at[t][sbeg + s];
#pragma unroll
    for (int j = 0; j < 4; ++j) {
      const float2 ev = *(const float2*)(ep + (size_t)(s + j) * DD);
#pragma unroll
      for (int t = 0; t < 8; ++t) {
        const float a = ((const float*)&av[t])[j];
        acc[t].x = fmaf(a, ev.x, acc[t].x);
        acc[t].y = fmaf(a, ev.y, acc[t].y);
      }
    }
  }
#pragma unroll
  for (int t = 0; t < 8; ++t)
    *(float2*)&red[w][t][dp] = acc[t];
  __syncthreads();

  // epilogue: 8t x 128d = 1024 outputs, one per thread; fixed q-order sum
  const int t = tx >> 7;                // 0..7
  const int d = tx & 127;
  float o = 0.f;
#pragma unroll
  for (int q = 0; q < 16; ++q) o += red[q][t][d];
  ctx[(size_t)(b * TD + tg * 8 + t) * DD + dt * 128 + d] = o;
}

extern "C" void kernel_launch(void* const* d_in, const int* in_sizes, int n_in,
                              void* d_out, int out_size, void* d_ws, size_t ws_size,
                              hipStream_t stream) {
  const float* dec = (const float*)d_in[0];
  const float* enc = (const float*)d_in[1];
  const float* W1  = (const float*)d_in[2];
  const float* b1  = (const float*)d_in[3];
  const float* W2  = (const float*)d_in[4];
  const float* b2  = (const float*)d_in[5];
  const float* v   = (const float*)d_in[6];
  // d_in[7] = v_b: skipped — softmax is invariant to a uniform score shift.

  float* ctx  = (float*)d_out;                        // [4,128,512]
  float* attn = (float*)d_out + (size_t)NB * TD * DD; // [4,128,1024]

  float* ws    = (float*)d_ws;
  float* wencT = ws;                                  // [4][128][1024] 2 MB (exp2-domain)
  float* wdec  = wencT + (size_t)NB * UN * SE;        // [512][128] 256 KB

  hipLaunchKernelGGL(k_proj, dim3(288), dim3(512), 0, stream,
                     enc, dec, W1, b1, W2, b2, wencT, wdec);
  hipLaunchKernelGGL(k_score, dim3(256), dim3(1024), 0, stream,
                     wdec, v, wencT, attn);
  hipLaunchKernelGGL(k_ctx, dim3(256), dim3(1024), 0, stream, attn, enc, ctx);
}